// Round 4
// baseline (25954.205 us; speedup 1.0000x reference)
//
#include <hip/hip_runtime.h>
#include <cstddef>
#include <math.h>

#define SEQ   256
#define BATCH 2048
#define FD    5
#define HD    64
#define NCOL  1280   // 256 gm cols + 1024 ga cols
#define ROWS  8
#define NTHR  512

// Accurate libm-based activations (match jax/np fp32 to ~1-2 ulp).
__device__ __forceinline__ float sigm(float x) { return 1.0f / (1.0f + expf(-x)); }
__device__ __forceinline__ float tanh_f(float x) { return tanhf(x); }

__device__ __forceinline__ float wave_sum(float v) {
#pragma unroll
    for (int m = 1; m < 64; m <<= 1) v += __shfl_xor(v, m);
    return v;
}

// Pre-transpose recurrent weights into Ut[col][h] (contiguous per column).
// col 0..255  -> U_main[:, col]        (U_main is [64][256])
// col 256..1279 -> U_aux[kk][:, gg]    (U_aux is [8][64][128]), kk=(col-256)/128
__global__ void transpose_u(const float* __restrict__ U_main,
                            const float* __restrict__ U_aux,
                            float* __restrict__ Ut) {
    const int c = blockIdx.x;
    const int h = threadIdx.x;
    float v;
    if (c < 256) {
        v = U_main[h * 256 + c];
    } else {
        int cp = c - 256, kk = cp >> 7, gg = cp & 127;
        v = U_aux[(size_t)kk * 64 * 128 + h * 128 + gg];
    }
    Ut[c * 64 + h] = v;
}

__global__ __launch_bounds__(NTHR, 2)
void minet_fused(const float* __restrict__ Y,
                 const float* __restrict__ x1, const float* __restrict__ x2,
                 const float* __restrict__ x3, const float* __restrict__ x4,
                 const float* __restrict__ x5, const float* __restrict__ x6,
                 const float* __restrict__ x7, const float* __restrict__ x8,
                 const float* __restrict__ W_main, const float* __restrict__ Ut,
                 const float* __restrict__ b_main, const float* __restrict__ W_aux,
                 const float* __restrict__ b_aux,
                 const float* __restrict__ W_att,  const float* __restrict__ b_att,
                 const float* __restrict__ W_ih,   const float* __restrict__ W_hh,
                 const float* __restrict__ b_ih,   const float* __restrict__ b_hh,
                 const float* __restrict__ lin_W,  const float* __restrict__ lin_b,
                 float* __restrict__ out)
{
    __shared__ __align__(16) float h1[ROWS][HD];
    __shared__ __align__(16) float c1[ROWS][HD];
    __shared__ __align__(16) float h2[ROWS][HD];
    __shared__ __align__(16) float outb[ROWS][NCOL];       // 40 KB
    __shared__ __align__(16) float outg[2][ROWS][256];     // 16 KB (ih-part, hh-part)
    __shared__ __align__(16) float inb[ROWS][9][8];        // slot 0 = Y, 1..8 = x1..x8
    __shared__ __align__(16) float WaT[HD * HD];           // 16 KB: WaT[g*64+h] = W_att[h][g]

    const int tid  = threadIdx.x;
    const int lane = tid & 63;
    const int wid  = tid >> 6;          // 8 waves; wave w owns batch row w for P4/P5/P7
    const int b0   = blockIdx.x * ROWS; // batch base
    const bool has3 = (tid < 256);      // threads owning a 3rd column

    // ---------- one-time setup ----------
    for (int i = tid; i < HD * HD; i += NTHR) {
        int g = i >> 6, h = i & 63;
        WaT[i] = W_att[h * 64 + g];
    }

    // column ownership: col[0]=tid, col[1]=tid+512, col[2]=tid+1024 (tid<256 only)
    int colv[3];
    colv[0] = tid; colv[1] = tid + 512; colv[2] = has3 ? tid + 1024 : 0;
    float wf[3][5];
    float bias[3];
    int   inoff[3];
    const float* utp[3];
#pragma unroll
    for (int j = 0; j < 3; ++j) {
        if (j < 2 || has3) {
            int c = colv[j];
            utp[j] = Ut + (size_t)c * 64;
            if (c < 256) {
#pragma unroll
                for (int f = 0; f < FD; ++f) wf[j][f] = W_main[f * 256 + c];
                bias[j]  = b_main[c];
                inoff[j] = 0;
            } else {
                int cp = c - 256, kk = cp >> 7, gg = cp & 127;
#pragma unroll
                for (int f = 0; f < FD; ++f) wf[j][f] = W_aux[(kk * 5 + f) * 128 + gg];
                bias[j]  = b_aux[kk * 128 + gg];
                inoff[j] = (1 + kk) * 8;
            }
        } else {
            utp[j] = Ut; bias[j] = 0.0f; inoff[j] = 0;
#pragma unroll
            for (int f = 0; f < FD; ++f) wf[j][f] = 0.0f;
        }
    }

    // LSTM2: thread owns one column of W_ih (tid<256) or W_hh (tid>=256)
    const int  cc      = tid & 255;
    const bool ispart1 = (tid >= 256);
    const float* wcol  = (ispart1 ? W_hh : W_ih) + (size_t)cc * 64;  // row-contiguous
    const float  b2    = ispart1 ? 0.0f : (b_ih[cc] + b_hh[cc]);

    const float linw = lin_W[lane];
    const float linb = lin_b[0];
    const float batt = b_att[0];

    // zero states
    for (int i = tid; i < ROWS * HD; i += NTHR) {
        (&h1[0][0])[i] = 0.0f; (&c1[0][0])[i] = 0.0f; (&h2[0][0])[i] = 0.0f;
    }
    for (int i = tid; i < ROWS * 9 * 8; i += NTHR) (&inb[0][0][0])[i] = 0.0f;
    float c2 = 0.0f;   // LSTM2 cell state: (row=wid, unit=lane)

    // input prefetch: 360 values = 8 rows x 9 slots x 5 feats (threads 0..359)
    const bool pon = (tid < 360);
    const float* psrc = Y;
    int pofs = 0;
    float pf = 0.0f;
    if (pon) {
        int r = tid / 45, rem = tid % 45;
        int s = rem / 5, f = rem % 5;
        const float* base = Y;
        if (s == 1) base = x1; else if (s == 2) base = x2; else if (s == 3) base = x3;
        else if (s == 4) base = x4; else if (s == 5) base = x5; else if (s == 6) base = x6;
        else if (s == 7) base = x7; else if (s == 8) base = x8;
        psrc = base + (size_t)(b0 + r) * FD + f;
        pofs = (r * 9 + s) * 8 + f;
        pf   = psrc[0];   // t = 0
    }

    for (int t = 0; t < SEQ; ++t) {
        // ---- P1: publish staged inputs for step t
        if (pon) (&inb[0][0][0])[pofs] = pf;
        __syncthreads();   // BAR_A: inb ready; prev-step h1/c1/h2 visible

        // prefetch t+1
        if (pon && t + 1 < SEQ) pf = psrc[(size_t)(t + 1) * BATCH * FD];

        // ---- P3: 1280-col dot  outb[r][c] = bias + in·wf + h1[r]·Ut[c]
        float acc[3][ROWS];
#pragma unroll
        for (int j = 0; j < 3; ++j) {
            if (j < 2 || has3) {
#pragma unroll
                for (int r = 0; r < ROWS; ++r) {
                    const float* ip = &inb[r][0][0] + inoff[j];
                    float4 ia = *(const float4*)ip;
                    float  i4 = ip[4];
                    acc[j][r] = bias[j] + ia.x * wf[j][0] + ia.y * wf[j][1] + ia.z * wf[j][2]
                                        + ia.w * wf[j][3] + i4 * wf[j][4];
                }
            }
        }
#pragma unroll 4
        for (int hb = 0; hb < 16; ++hb) {
            float4 hreg[ROWS];
#pragma unroll
            for (int r = 0; r < ROWS; ++r) hreg[r] = *(const float4*)&h1[r][hb * 4];
            float4 w0 = *(const float4*)(utp[0] + hb * 4);
            float4 w1 = *(const float4*)(utp[1] + hb * 4);
#pragma unroll
            for (int r = 0; r < ROWS; ++r)
                acc[0][r] = fmaf(hreg[r].x, w0.x, fmaf(hreg[r].y, w0.y,
                            fmaf(hreg[r].z, w0.z, fmaf(hreg[r].w, w0.w, acc[0][r]))));
#pragma unroll
            for (int r = 0; r < ROWS; ++r)
                acc[1][r] = fmaf(hreg[r].x, w1.x, fmaf(hreg[r].y, w1.y,
                            fmaf(hreg[r].z, w1.z, fmaf(hreg[r].w, w1.w, acc[1][r]))));
            if (has3) {
                float4 w2 = *(const float4*)(utp[2] + hb * 4);
#pragma unroll
                for (int r = 0; r < ROWS; ++r)
                    acc[2][r] = fmaf(hreg[r].x, w2.x, fmaf(hreg[r].y, w2.y,
                                fmaf(hreg[r].z, w2.z, fmaf(hreg[r].w, w2.w, acc[2][r]))));
            }
        }
#pragma unroll
        for (int j = 0; j < 3; ++j) {
            if (j < 2 || has3) {
#pragma unroll
                for (int r = 0; r < ROWS; ++r)
                    outb[r][colv[j]] = acc[j][r];
            }
        }

        // ---- P4b: v[h=lane] = sum_g W_att[h,g] * c_prev[wid][g]
        float v0 = 0.0f;
        {
            float cr0 = c1[wid][lane];
#pragma unroll
            for (int g = 0; g < 64; ++g) {
                float w = WaT[g * 64 + lane];
                v0 = fmaf(__shfl(cr0, g), w, v0);
            }
        }
        __syncthreads();   // BAR_B: outb ready

        // ---- P5: gates + attention softmax + MI state update (wave wid -> row wid)
        {
            const int r = wid;
            float gi = outb[r][lane],       gf = outb[r][64 + lane];
            float go = outb[r][128 + lane], gc = outb[r][192 + lane];
            float ii = sigm(gi), ff = sigm(gf), oo = sigm(go), cm = tanh_f(gc);
            float l[9];
            l[0] = ii * cm;
#pragma unroll
            for (int k = 1; k <= 8; ++k) {
                float a_ = outb[r][256 + (k - 1) * 128 + lane];
                float b_ = outb[r][256 + (k - 1) * 128 + 64 + lane];
                l[k] = sigm(a_) * tanh_f(b_);
            }
            float u[9]; float umax = -1e30f;
#pragma unroll
            for (int k = 0; k < 9; ++k) {
                float p = wave_sum(l[k] * v0);
                u[k] = tanh_f(p + batt);
                umax = fmaxf(umax, u[k]);
            }
            float den = 0.0f, Lh = 0.0f;
#pragma unroll
            for (int k = 0; k < 9; ++k) {
                float e = expf(u[k] - umax);
                den += e;
                Lh = fmaf(e, l[k], Lh);
            }
            Lh /= den;
            float cp = c1[r][lane];
            float cn = fmaf(ff, cp, Lh);
            float hn = oo * tanh_f(cn);
            c1[r][lane] = cn;
            h1[r][lane] = hn;
        }
        __syncthreads();   // BAR_C: h1 (hs[t]) ready

        // ---- P6: LSTM2 pre-activations, streamed weights (1 col/thread)
        {
            float accg[ROWS];
#pragma unroll
            for (int r = 0; r < ROWS; ++r) accg[r] = b2;
            const float(*SS)[HD] = ispart1 ? h2 : h1;
#pragma unroll 4
            for (int hb = 0; hb < 16; ++hb) {
                float4 w4 = *(const float4*)(wcol + hb * 4);
#pragma unroll
                for (int r = 0; r < ROWS; ++r) {
                    float4 s4 = *(const float4*)&SS[r][hb * 4];
                    accg[r] = fmaf(s4.x, w4.x, fmaf(s4.y, w4.y,
                              fmaf(s4.z, w4.z, fmaf(s4.w, w4.w, accg[r]))));
                }
            }
#pragma unroll
            for (int r = 0; r < ROWS; ++r)
                outg[ispart1 ? 1 : 0][r][cc] = accg[r];
        }
        __syncthreads();   // BAR_D: outg ready

        // ---- P7: LSTM2 gates (torch order i,f,g,o) + output projection (row wid)
        {
            const int r = wid;
            float g0 = outg[0][r][lane]       + outg[1][r][lane];
            float g1 = outg[0][r][64 + lane]  + outg[1][r][64 + lane];
            float g2 = outg[0][r][128 + lane] + outg[1][r][128 + lane];
            float g3 = outg[0][r][192 + lane] + outg[1][r][192 + lane];
            float i2 = sigm(g0), f2 = sigm(g1), gg = tanh_f(g2), o2 = sigm(g3);
            float cn = fmaf(f2, c2, i2 * gg);
            c2 = cn;
            float hn = o2 * tanh_f(cn);
            h2[r][lane] = hn;
            float e = wave_sum(fmaxf(hn, 0.0f) * linw);
            if (lane == 0) out[(size_t)t * BATCH + b0 + r] = e + linb;
        }
        // next-iteration BAR_A separates h2 writes from P6 reads
    }
}

extern "C" void kernel_launch(void* const* d_in, const int* in_sizes, int n_in,
                              void* d_out, int out_size, void* d_ws, size_t ws_size,
                              hipStream_t stream) {
    const float* Y      = (const float*)d_in[0];
    const float* x1     = (const float*)d_in[1];
    const float* x2     = (const float*)d_in[2];
    const float* x3     = (const float*)d_in[3];
    const float* x4     = (const float*)d_in[4];
    const float* x5     = (const float*)d_in[5];
    const float* x6     = (const float*)d_in[6];
    const float* x7     = (const float*)d_in[7];
    const float* x8     = (const float*)d_in[8];
    const float* W_main = (const float*)d_in[9];
    const float* U_main = (const float*)d_in[10];
    const float* b_main = (const float*)d_in[11];
    const float* W_aux  = (const float*)d_in[12];
    const float* U_aux  = (const float*)d_in[13];
    const float* b_aux  = (const float*)d_in[14];
    const float* W_att  = (const float*)d_in[15];
    const float* b_att  = (const float*)d_in[16];
    const float* W_ih   = (const float*)d_in[17];
    const float* W_hh   = (const float*)d_in[18];
    const float* b_ih   = (const float*)d_in[19];
    const float* b_hh   = (const float*)d_in[20];
    const float* lin_W  = (const float*)d_in[21];
    const float* lin_b  = (const float*)d_in[22];
    float* out = (float*)d_out;
    float* Ut  = (float*)d_ws;   // 1280*64 fp32 = 320 KB

    transpose_u<<<dim3(NCOL), dim3(HD), 0, stream>>>(U_main, U_aux, Ut);

    dim3 grid(BATCH / ROWS);   // 256 blocks, 8 batch rows each, 1 block/CU
    dim3 block(NTHR);          // 8 waves/CU
    minet_fused<<<grid, block, 0, stream>>>(Y, x1, x2, x3, x4, x5, x6, x7, x8,
                                            W_main, Ut, b_main, W_aux, b_aux,
                                            W_att, b_att, W_ih, W_hh, b_ih, b_hh,
                                            lin_W, lin_b, out);
}

// Round 5
// 7572.779 us; speedup vs baseline: 3.4273x; 3.4273x over previous
//
#include <hip/hip_runtime.h>
#include <cstddef>
#include <math.h>

#define SEQ   256
#define BATCH 2048
#define FD    5
#define HD    64
#define NCOL  1280   // 256 gm cols + 1024 ga cols
#define ROWS  8
#define NTHR  512

// Accurate libm-based activations (match jax/np fp32 to ~1-2 ulp).
__device__ __forceinline__ float sigm(float x) { return 1.0f / (1.0f + expf(-x)); }
__device__ __forceinline__ float tanh_f(float x) { return tanhf(x); }

__device__ __forceinline__ float wave_sum(float v) {
#pragma unroll
    for (int m = 1; m < 64; m <<= 1) v += __shfl_xor(v, m);
    return v;
}

// Pre-transpose recurrent weights into Ut[col][h] (contiguous per column).
__global__ void transpose_u(const float* __restrict__ U_main,
                            const float* __restrict__ U_aux,
                            float* __restrict__ Ut) {
    const int c = blockIdx.x;
    const int h = threadIdx.x;
    float v;
    if (c < 256) {
        v = U_main[h * 256 + c];
    } else {
        int cp = c - 256, kk = cp >> 7, gg = cp & 127;
        v = U_aux[(size_t)kk * 64 * 128 + h * 128 + gg];
    }
    Ut[c * 64 + h] = v;
}

// NOTE: second launch-bounds arg of 2 at 512 threads forced VGPR=128 and 56GB/launch
// of scratch spills (round-4 regression). Keep it at 1: ≤256 VGPR still gives 2 waves/SIMD.
__global__ __launch_bounds__(NTHR, 1)
void minet_fused(const float* __restrict__ Y,
                 const float* __restrict__ x1, const float* __restrict__ x2,
                 const float* __restrict__ x3, const float* __restrict__ x4,
                 const float* __restrict__ x5, const float* __restrict__ x6,
                 const float* __restrict__ x7, const float* __restrict__ x8,
                 const float* __restrict__ W_main, const float* __restrict__ Ut,
                 const float* __restrict__ b_main, const float* __restrict__ W_aux,
                 const float* __restrict__ b_aux,
                 const float* __restrict__ W_att,  const float* __restrict__ b_att,
                 const float* __restrict__ W_ih,   const float* __restrict__ W_hh,
                 const float* __restrict__ b_ih,   const float* __restrict__ b_hh,
                 const float* __restrict__ lin_W,  const float* __restrict__ lin_b,
                 float* __restrict__ out)
{
    __shared__ __align__(16) float h1[ROWS][HD];
    __shared__ __align__(16) float c1[ROWS][HD];
    __shared__ __align__(16) float h2[ROWS][HD];
    __shared__ __align__(16) float outb[ROWS][NCOL];       // 40 KB
    __shared__ __align__(16) float outg[2][ROWS][256];     // 16 KB (ih-part, hh-part)
    __shared__ __align__(16) float inb[ROWS][9][8];        // slot 0 = Y, 1..8 = x1..x8
    __shared__ __align__(16) float WaT[HD * HD];           // 16 KB: WaT[g*64+h] = W_att[h][g]

    const int tid  = threadIdx.x;
    const int lane = tid & 63;
    const int wid  = tid >> 6;          // 8 waves; wave w owns batch row w for P4/P5/P7
    const int b0   = blockIdx.x * ROWS; // batch base
    const bool has3 = (tid < 256);      // threads owning a 3rd column

    // ---------- one-time setup ----------
    for (int i = tid; i < HD * HD; i += NTHR) {
        int g = i >> 6, h = i & 63;
        WaT[i] = W_att[h * 64 + g];
    }

    // column ownership: col[0]=tid, col[1]=tid+512, col[2]=tid+1024 (tid<256 only)
    int colv[3];
    colv[0] = tid; colv[1] = tid + 512; colv[2] = has3 ? tid + 1024 : 0;
    float wf[3][5];
    float bias[3];
    int   inoff[3];
    const float* utp[3];
#pragma unroll
    for (int j = 0; j < 3; ++j) {
        if (j < 2 || has3) {
            int c = colv[j];
            utp[j] = Ut + (size_t)c * 64;
            if (c < 256) {
#pragma unroll
                for (int f = 0; f < FD; ++f) wf[j][f] = W_main[f * 256 + c];
                bias[j]  = b_main[c];
                inoff[j] = 0;
            } else {
                int cp = c - 256, kk = cp >> 7, gg = cp & 127;
#pragma unroll
                for (int f = 0; f < FD; ++f) wf[j][f] = W_aux[(kk * 5 + f) * 128 + gg];
                bias[j]  = b_aux[kk * 128 + gg];
                inoff[j] = (1 + kk) * 8;
            }
        } else {
            utp[j] = Ut; bias[j] = 0.0f; inoff[j] = 0;
#pragma unroll
            for (int f = 0; f < FD; ++f) wf[j][f] = 0.0f;
        }
    }

    // LSTM2: thread owns one column of W_ih (tid<256) or W_hh (tid>=256)
    const int  cc      = tid & 255;
    const bool ispart1 = (tid >= 256);
    const float* wcol  = (ispart1 ? W_hh : W_ih) + (size_t)cc * 64;  // row-contiguous
    const float  b2    = ispart1 ? 0.0f : (b_ih[cc] + b_hh[cc]);

    const float linw = lin_W[lane];
    const float linb = lin_b[0];
    const float batt = b_att[0];

    // zero states
    for (int i = tid; i < ROWS * HD; i += NTHR) {
        (&h1[0][0])[i] = 0.0f; (&c1[0][0])[i] = 0.0f; (&h2[0][0])[i] = 0.0f;
    }
    for (int i = tid; i < ROWS * 9 * 8; i += NTHR) (&inb[0][0][0])[i] = 0.0f;
    float c2 = 0.0f;   // LSTM2 cell state: (row=wid, unit=lane)

    // input prefetch: 360 values = 8 rows x 9 slots x 5 feats (threads 0..359)
    const bool pon = (tid < 360);
    const float* psrc = Y;
    int pofs = 0;
    float pf = 0.0f;
    if (pon) {
        int r = tid / 45, rem = tid % 45;
        int s = rem / 5, f = rem % 5;
        const float* base = Y;
        if (s == 1) base = x1; else if (s == 2) base = x2; else if (s == 3) base = x3;
        else if (s == 4) base = x4; else if (s == 5) base = x5; else if (s == 6) base = x6;
        else if (s == 7) base = x7; else if (s == 8) base = x8;
        psrc = base + (size_t)(b0 + r) * FD + f;
        pofs = (r * 9 + s) * 8 + f;
        pf   = psrc[0];   // t = 0
    }

    for (int t = 0; t < SEQ; ++t) {
        // ---- P1: publish staged inputs for step t
        if (pon) (&inb[0][0][0])[pofs] = pf;
        __syncthreads();   // BAR_A: inb ready; prev-step h1/c1/h2 visible

        // prefetch t+1
        if (pon && t + 1 < SEQ) pf = psrc[(size_t)(t + 1) * BATCH * FD];

        // ---- P3: 1280-col dot  outb[r][c] = bias + in·wf + h1[r]·Ut[c]
        float acc[3][ROWS];
#pragma unroll
        for (int j = 0; j < 3; ++j) {
            if (j < 2 || has3) {
#pragma unroll
                for (int r = 0; r < ROWS; ++r) {
                    const float* ip = &inb[r][0][0] + inoff[j];
                    float4 ia = *(const float4*)ip;
                    float  i4 = ip[4];
                    acc[j][r] = bias[j] + ia.x * wf[j][0] + ia.y * wf[j][1] + ia.z * wf[j][2]
                                        + ia.w * wf[j][3] + i4 * wf[j][4];
                }
            }
        }
#pragma unroll 2
        for (int hb = 0; hb < 16; ++hb) {
            // row-inner structure keeps live set small: w0..w2 (12) + one h4 (4) + acc (24)
            float4 w0 = *(const float4*)(utp[0] + hb * 4);
            float4 w1 = *(const float4*)(utp[1] + hb * 4);
            float4 w2 = has3 ? *(const float4*)(utp[2] + hb * 4) : w0;
#pragma unroll
            for (int r = 0; r < ROWS; ++r) {
                float4 h4 = *(const float4*)&h1[r][hb * 4];
                acc[0][r] = fmaf(h4.x, w0.x, fmaf(h4.y, w0.y,
                            fmaf(h4.z, w0.z, fmaf(h4.w, w0.w, acc[0][r]))));
                acc[1][r] = fmaf(h4.x, w1.x, fmaf(h4.y, w1.y,
                            fmaf(h4.z, w1.z, fmaf(h4.w, w1.w, acc[1][r]))));
                if (has3)
                    acc[2][r] = fmaf(h4.x, w2.x, fmaf(h4.y, w2.y,
                                fmaf(h4.z, w2.z, fmaf(h4.w, w2.w, acc[2][r]))));
            }
        }
#pragma unroll
        for (int j = 0; j < 3; ++j) {
            if (j < 2 || has3) {
#pragma unroll
                for (int r = 0; r < ROWS; ++r)
                    outb[r][colv[j]] = acc[j][r];
            }
        }

        // ---- P4b: v[h=lane] = sum_g W_att[h,g] * c_prev[wid][g]
        float v0 = 0.0f;
        {
            float cr0 = c1[wid][lane];
#pragma unroll
            for (int g = 0; g < 64; ++g) {
                float w = WaT[g * 64 + lane];
                v0 = fmaf(__shfl(cr0, g), w, v0);
            }
        }
        __syncthreads();   // BAR_B: outb ready

        // ---- P5: gates + attention softmax + MI state update (wave wid -> row wid)
        {
            const int r = wid;
            float gi = outb[r][lane],       gf = outb[r][64 + lane];
            float go = outb[r][128 + lane], gc = outb[r][192 + lane];
            float ii = sigm(gi), ff = sigm(gf), oo = sigm(go), cm = tanh_f(gc);
            float l[9];
            l[0] = ii * cm;
#pragma unroll
            for (int k = 1; k <= 8; ++k) {
                float a_ = outb[r][256 + (k - 1) * 128 + lane];
                float b_ = outb[r][256 + (k - 1) * 128 + 64 + lane];
                l[k] = sigm(a_) * tanh_f(b_);
            }
            float u[9]; float umax = -1e30f;
#pragma unroll
            for (int k = 0; k < 9; ++k) {
                float p = wave_sum(l[k] * v0);
                u[k] = tanh_f(p + batt);
                umax = fmaxf(umax, u[k]);
            }
            float den = 0.0f, Lh = 0.0f;
#pragma unroll
            for (int k = 0; k < 9; ++k) {
                float e = expf(u[k] - umax);
                den += e;
                Lh = fmaf(e, l[k], Lh);
            }
            Lh /= den;
            float cp = c1[r][lane];
            float cn = fmaf(ff, cp, Lh);
            float hn = oo * tanh_f(cn);
            c1[r][lane] = cn;
            h1[r][lane] = hn;
        }
        __syncthreads();   // BAR_C: h1 (hs[t]) ready

        // ---- P6: LSTM2 pre-activations, streamed weights (1 col/thread)
        {
            float accg[ROWS];
#pragma unroll
            for (int r = 0; r < ROWS; ++r) accg[r] = b2;
            const float(*SS)[HD] = ispart1 ? h2 : h1;
#pragma unroll 4
            for (int hb = 0; hb < 16; ++hb) {
                float4 w4 = *(const float4*)(wcol + hb * 4);
#pragma unroll
                for (int r = 0; r < ROWS; ++r) {
                    float4 s4 = *(const float4*)&SS[r][hb * 4];
                    accg[r] = fmaf(s4.x, w4.x, fmaf(s4.y, w4.y,
                              fmaf(s4.z, w4.z, fmaf(s4.w, w4.w, accg[r]))));
                }
            }
#pragma unroll
            for (int r = 0; r < ROWS; ++r)
                outg[ispart1 ? 1 : 0][r][cc] = accg[r];
        }
        __syncthreads();   // BAR_D: outg ready

        // ---- P7: LSTM2 gates (torch order i,f,g,o) + output projection (row wid)
        {
            const int r = wid;
            float g0 = outg[0][r][lane]       + outg[1][r][lane];
            float g1 = outg[0][r][64 + lane]  + outg[1][r][64 + lane];
            float g2 = outg[0][r][128 + lane] + outg[1][r][128 + lane];
            float g3 = outg[0][r][192 + lane] + outg[1][r][192 + lane];
            float i2 = sigm(g0), f2 = sigm(g1), gg = tanh_f(g2), o2 = sigm(g3);
            float cn = fmaf(f2, c2, i2 * gg);
            c2 = cn;
            float hn = o2 * tanh_f(cn);
            h2[r][lane] = hn;
            float e = wave_sum(fmaxf(hn, 0.0f) * linw);
            if (lane == 0) out[(size_t)t * BATCH + b0 + r] = e + linb;
        }
        // next-iteration BAR_A separates h2 writes from P6 reads
    }
}

extern "C" void kernel_launch(void* const* d_in, const int* in_sizes, int n_in,
                              void* d_out, int out_size, void* d_ws, size_t ws_size,
                              hipStream_t stream) {
    const float* Y      = (const float*)d_in[0];
    const float* x1     = (const float*)d_in[1];
    const float* x2     = (const float*)d_in[2];
    const float* x3     = (const float*)d_in[3];
    const float* x4     = (const float*)d_in[4];
    const float* x5     = (const float*)d_in[5];
    const float* x6     = (const float*)d_in[6];
    const float* x7     = (const float*)d_in[7];
    const float* x8     = (const float*)d_in[8];
    const float* W_main = (const float*)d_in[9];
    const float* U_main = (const float*)d_in[10];
    const float* b_main = (const float*)d_in[11];
    const float* W_aux  = (const float*)d_in[12];
    const float* U_aux  = (const float*)d_in[13];
    const float* b_aux  = (const float*)d_in[14];
    const float* W_att  = (const float*)d_in[15];
    const float* b_att  = (const float*)d_in[16];
    const float* W_ih   = (const float*)d_in[17];
    const float* W_hh   = (const float*)d_in[18];
    const float* b_ih   = (const float*)d_in[19];
    const float* b_hh   = (const float*)d_in[20];
    const float* lin_W  = (const float*)d_in[21];
    const float* lin_b  = (const float*)d_in[22];
    float* out = (float*)d_out;
    float* Ut  = (float*)d_ws;   // 1280*64 fp32 = 320 KB

    transpose_u<<<dim3(NCOL), dim3(HD), 0, stream>>>(U_main, U_aux, Ut);

    dim3 grid(BATCH / ROWS);   // 256 blocks, 8 batch rows each, 1 block/CU
    dim3 block(NTHR);          // 8 waves/CU
    minet_fused<<<grid, block, 0, stream>>>(Y, x1, x2, x3, x4, x5, x6, x7, x8,
                                            W_main, Ut, b_main, W_aux, b_aux,
                                            W_att, b_att, W_ih, W_hh, b_ih, b_hh,
                                            lin_W, lin_b, out);
}